// Round 4
// baseline (600.854 us; speedup 1.0000x reference)
//
#include <hip/hip_runtime.h>
#include <hip/hip_bf16.h>
#include <stdint.h>

// Problem: B=32, T=2048, D=1024, U=1024, all fp32 in/out.
// out = [context 32*1024, attention_weights 32*2048]
//
// ws layout:
//   [0, 2MB)            W1f bf16 — W1 packed in MFMA B-fragment order:
//                       frag(ut,ks) = 1KB block; elem(lane,j) =
//                       W1[k = ks*32 + (lane>>4)*8 + j][u = ut*16 + (lane&15)]
//   [2MB, +128KB)       qp2 fp32 [B][U] = query@W2 + b2 + b1
//   [2MB+128KB,+256KB)  score fp32 [B][T]
#define WS_W1F   0
#define WS_QP2   2097152
#define WS_SCORE (2097152 + 131072)

typedef __attribute__((ext_vector_type(8))) short bf16x8;
typedef __attribute__((ext_vector_type(4))) float f32x4;

__device__ inline uint16_t f2b(float f) {
    __hip_bfloat16 h = __float2bfloat16(f);
    return *reinterpret_cast<uint16_t*>(&h);
}

// ---------------- Kernel 1: prep = W1 repack + qp2 + ctx zero ----------------
// blocks 0..127 (16 waves each): repack 16 fragments -> W1f (2048 x 1KB frags)
// blocks 128..159: qp2[b][u] = b1[u]+b2[u]+query[b]@W2[:,u], one u per thread;
//                  also zero ctx[b].
__global__ __launch_bounds__(1024) void k_prep(const float* __restrict__ W1,
                                               const float* __restrict__ query,
                                               const float* __restrict__ W2,
                                               const float* __restrict__ b1,
                                               const float* __restrict__ b2,
                                               __hip_bfloat16* __restrict__ W1f,
                                               float* __restrict__ qp2,
                                               float* __restrict__ ctx_out) {
    int blk = blockIdx.x, tid = threadIdx.x;
    if (blk < 128) {
        int lane = tid & 63, w = tid >> 6;     // 16 waves, one frag each
        int l15 = lane & 15, quad = lane >> 4;
        int frag = blk * 16 + w;               // 0..2047
        int ut = frag >> 5, ks = frag & 31;
        union { uint16_t h[8]; int4 v; } pk;
        #pragma unroll
        for (int j = 0; j < 8; ++j) {
            float x = W1[(size_t)(ks * 32 + quad * 8 + j) * 1024 + ut * 16 + l15];
            pk.h[j] = f2b(x);
        }
        *(int4*)((char*)W1f + (size_t)frag * 1024 + lane * 16) = pk.v;
    } else {
        int b = blk - 128;
        int u = tid;
        float a = b1[u] + b2[u];
        const float* q = query + b * 1024;
        const float* Wp = W2 + u;
        #pragma unroll 8
        for (int d = 0; d < 1024; ++d)
            a += q[d] * Wp[(size_t)d * 1024];
        qp2[b * 1024 + u] = a;
        ctx_out[b * 1024 + u] = 0.f;
    }
}

// ---------------- Kernel 2: fused score = tanh(values@W1 + qp2) @ V ----------
// Grid 1024 = 32 b * 32 row-tiles of 64. Block 512 (8 waves, 2/SIMD).
// A resident in LDS (64 rows x 1024 k bf16, XOR-swizzled 16B chunks, 0 conflicts);
//   A-stage loads are NON-TEMPORAL so the streaming values traffic doesn't
//   evict W1f from L2 (B is read 1024x = 2GB; must be L2-served).
// B from global in fragment-packed order: one coalesced 1KB segment per load.
// Wave w owns u-stripe [w*128, w*128+128): rt=4 (64 rows), ct=8.
__global__ __launch_bounds__(512, 1) void k_score(
        const float* __restrict__ values, const __hip_bfloat16* __restrict__ W1f,
        const float* __restrict__ qp2, const float* __restrict__ V,
        float* __restrict__ score) {
    extern __shared__ char smem[];
    uint16_t* Al = (uint16_t*)smem;             // 64 x 1024 bf16 (swizzled)
    float* red = (float*)(smem + 131072);       // [8 stripes][64 rows]

    const int tid = threadIdx.x;
    const int lane = tid & 63, w = tid >> 6;
    const int quad = lane >> 4, l15 = lane & 15;
    const int b = blockIdx.x >> 5, trow0 = (blockIdx.x & 31) << 6;

    // ---- stage A: values[b, trow0..+64, :] fp32 -> bf16 LDS (once, nt) ----
    const float* Ag = values + (size_t)(b * 2048 + trow0) * 1024;
    #pragma unroll
    for (int i = 0; i < 16; ++i) {
        int id = i * 512 + tid;
        int row = id >> 7, c = id & 127;
        const f32x4* src = (const f32x4*)(Ag + (size_t)row * 1024 + c * 8);
        f32x4 v0 = __builtin_nontemporal_load(src);
        f32x4 v1 = __builtin_nontemporal_load(src + 1);
        union { uint16_t h[8]; int4 v; } pk;
        pk.h[0]=f2b(v0.x); pk.h[1]=f2b(v0.y); pk.h[2]=f2b(v0.z); pk.h[3]=f2b(v0.w);
        pk.h[4]=f2b(v1.x); pk.h[5]=f2b(v1.y); pk.h[6]=f2b(v1.z); pk.h[7]=f2b(v1.w);
        int pos = (c & 112) | ((c & 15) ^ (row & 15));
        *(int4*)(Al + (size_t)row * 1024 + pos * 8) = pk.v;
    }
    __syncthreads();   // only barrier before the final reduction

    // per-lane fragment base: frag(ut = w*8 + ct, ks) at byte (ut*32+ks)*1024
    const char* Bbase = (const char*)W1f + (size_t)(w * 8) * 32768 + lane * 16;

    f32x4 acc[4][8];
    #pragma unroll
    for (int rt = 0; rt < 4; ++rt)
        #pragma unroll
        for (int ct = 0; ct < 8; ++ct) acc[rt][ct] = (f32x4){0.f, 0.f, 0.f, 0.f};

    bf16x8 af[2][4], bfr[2][8];
    {   // prologue: ks = 0
        int pos = (quad & 15) ^ l15;   // cb = quad
        #pragma unroll
        for (int rt = 0; rt < 4; ++rt)
            af[0][rt] = *(bf16x8*)(Al + (rt * 16 + l15) * 1024 + pos * 8);
        #pragma unroll
        for (int ct = 0; ct < 8; ++ct)
            bfr[0][ct] = *(const bf16x8*)(Bbase + (size_t)(ct * 32) * 1024);
    }

    #pragma unroll 2
    for (int ks = 0; ks < 32; ++ks) {
        int cur = ks & 1, nxt = cur ^ 1;
        if (ks < 31) {
            int cb = (ks + 1) * 4 + quad;
            int pos = (cb & 112) | ((cb & 15) ^ l15);
            #pragma unroll
            for (int rt = 0; rt < 4; ++rt)
                af[nxt][rt] = *(bf16x8*)(Al + (rt * 16 + l15) * 1024 + pos * 8);
            #pragma unroll
            for (int ct = 0; ct < 8; ++ct)
                bfr[nxt][ct] = *(const bf16x8*)(Bbase + (size_t)(ct * 32 + ks + 1) * 1024);
        }
        #pragma unroll
        for (int rt = 0; rt < 4; ++rt)
            #pragma unroll
            for (int ct = 0; ct < 8; ++ct)
                acc[rt][ct] = __builtin_amdgcn_mfma_f32_16x16x32_bf16(
                    af[cur][rt], bfr[cur][ct], acc[rt][ct], 0, 0, 0);
    }

    // ---- epilogue: tanh(acc + qp2[u]) * V[u], per-lane row partials ----
    float srow[4][4];
    #pragma unroll
    for (int rt = 0; rt < 4; ++rt)
        #pragma unroll
        for (int r = 0; r < 4; ++r) srow[rt][r] = 0.f;
    #pragma unroll
    for (int ct = 0; ct < 8; ++ct) {
        int u = w * 128 + ct * 16 + l15;
        float qv = qp2[b * 1024 + u];
        float vv = V[u];
        #pragma unroll
        for (int rt = 0; rt < 4; ++rt)
            #pragma unroll
            for (int r = 0; r < 4; ++r) {
                float x = acc[rt][ct][r] + qv;
                float e = __expf(2.f * x);
                float t = 1.f - 2.f * __builtin_amdgcn_rcpf(1.f + e);
                srow[rt][r] += t * vv;
            }
    }

    // reduce u: over 16 lanes (l15), then over the 8 wave-stripes via LDS
    #pragma unroll
    for (int rt = 0; rt < 4; ++rt)
        #pragma unroll
        for (int r = 0; r < 4; ++r) {
            float s = srow[rt][r];
            s += __shfl_xor(s, 1, 64);
            s += __shfl_xor(s, 2, 64);
            s += __shfl_xor(s, 4, 64);
            s += __shfl_xor(s, 8, 64);
            srow[rt][r] = s;
        }
    if (l15 == 0) {
        #pragma unroll
        for (int rt = 0; rt < 4; ++rt)
            #pragma unroll
            for (int r = 0; r < 4; ++r)
                red[w * 64 + rt * 16 + quad * 4 + r] = srow[rt][r];
    }
    __syncthreads();
    if (tid < 64) {
        float s = 0.f;
        #pragma unroll
        for (int k = 0; k < 8; ++k) s += red[k * 64 + tid];
        score[b * 2048 + trow0 + tid] = s;
    }
}

// ---------------- Kernel 3: softmax (recomputed per block) + weights + ctx ---
// Grid 512 = 32 b * 16 t-slices of 128. Each block computes the full softmax
// stats for its b (8KB score read, L2-hot), writes its attw slice, then
// accumulates its slice's contribution to context via atomicAdd.
__global__ __launch_bounds__(256) void k_out(const float* __restrict__ values,
                                             const float* __restrict__ score,
                                             float* __restrict__ out) {
    __shared__ float red[8];
    __shared__ float wl[128];
    int b = blockIdx.x >> 4, ts = blockIdx.x & 15, tid = threadIdx.x;
    const float* sc = score + b * 2048;
    float s[8]; float m = -1e30f;
    #pragma unroll
    for (int j = 0; j < 8; ++j) {
        s[j] = sc[j * 256 + tid];
        m = fmaxf(m, s[j]);
    }
    for (int off = 32; off; off >>= 1) m = fmaxf(m, __shfl_xor(m, off, 64));
    if ((tid & 63) == 0) red[tid >> 6] = m;
    __syncthreads();
    m = fmaxf(fmaxf(red[0], red[1]), fmaxf(red[2], red[3]));
    float sum = 0.f;
    #pragma unroll
    for (int j = 0; j < 8; ++j) sum += __expf(s[j] - m);
    for (int off = 32; off; off >>= 1) sum += __shfl_xor(sum, off, 64);
    if ((tid & 63) == 0) red[4 + (tid >> 6)] = sum;
    __syncthreads();
    sum = red[4] + red[5] + red[6] + red[7];
    float inv = __builtin_amdgcn_rcpf(sum);
    if (tid < 128) {
        float wv = __expf(sc[ts * 128 + tid] - m) * inv;
        wl[tid] = wv;
        out[32768 + b * 2048 + ts * 128 + tid] = wv;
    }
    __syncthreads();
    const f32x4* vb = (const f32x4*)(values + ((size_t)(b * 2048 + ts * 128)) * 1024 + tid * 4);
    f32x4 a = (f32x4){0.f, 0.f, 0.f, 0.f};
    #pragma unroll 8
    for (int t = 0; t < 128; ++t) {
        f32x4 v = vb[t * 256];
        a += wl[t] * v;
    }
    float* o = out + b * 1024 + tid * 4;
    atomicAdd(o + 0, a.x); atomicAdd(o + 1, a.y);
    atomicAdd(o + 2, a.z); atomicAdd(o + 3, a.w);
}

extern "C" void kernel_launch(void* const* d_in, const int* in_sizes, int n_in,
                              void* d_out, int out_size, void* d_ws, size_t ws_size,
                              hipStream_t stream) {
    const float* query  = (const float*)d_in[0];
    const float* values = (const float*)d_in[1];
    const float* W1 = (const float*)d_in[2];
    const float* b1 = (const float*)d_in[3];
    const float* W2 = (const float*)d_in[4];
    const float* b2 = (const float*)d_in[5];
    const float* V  = (const float*)d_in[6];
    // d_in[7] = bv: adds a constant pre-softmax -> cancels in softmax; unused.

    char* ws = (char*)d_ws;
    __hip_bfloat16* W1f = (__hip_bfloat16*)(ws + WS_W1F);
    float* qp2   = (float*)(ws + WS_QP2);
    float* score = (float*)(ws + WS_SCORE);
    float* out = (float*)d_out;

    (void)hipFuncSetAttribute((const void*)k_score,
                              hipFuncAttributeMaxDynamicSharedMemorySize, 133120);

    k_prep<<<160, 1024, 0, stream>>>(W1, query, W2, b1, b2, W1f, qp2, out);
    k_score<<<1024, 512, 133120, stream>>>(values, W1f, qp2, V, score);
    k_out<<<512, 256, 0, stream>>>(values, score, out);
}